// Round 2
// baseline (1305.633 us; speedup 1.0000x reference)
//
#include <hip/hip_runtime.h>

#define H 128

// ---------------- count per destination node ----------------
__global__ __launch_bounds__(256) void count_kernel(const int* __restrict__ ei,
                                                    int* __restrict__ cnt, int E) {
    int i = blockIdx.x * 256 + threadIdx.x;
    if (i < E) atomicAdd(&cnt[ei[E + i]], 1);
}

__global__ __launch_bounds__(256) void denom_kernel(const int* __restrict__ cnt,
                                                    float* __restrict__ invd, int N) {
    int i = blockIdx.x * 256 + threadIdx.x;
    if (i < N) {
        int c = cnt[i];
        invd[i] = 1.0f / (float)(c > 1 ? c : 1);
    }
}

// ---------------- init output with v (first nv4 float4s) then s ----------------
__global__ __launch_bounds__(256) void init_kernel(const float4* __restrict__ v,
                                                   const float4* __restrict__ s,
                                                   float4* __restrict__ out,
                                                   int nv4, int ns4) {
    int total = nv4 + ns4;
    for (int i = blockIdx.x * 256 + threadIdx.x; i < total; i += gridDim.x * 256) {
        out[i] = (i < nv4) ? v[i] : s[i - nv4];
    }
}

// ---------------- fused embed net: sexp = tanh(s@W1+b1)@W2+b2 ----------------
// 64 rows per block, 256 threads: col = tid&127, half = tid>>7 handles 32 rows.
// LDS reads are wave-broadcast (same address across lanes) -> conflict-free.
__global__ __launch_bounds__(256) void embed_kernel(const float* __restrict__ s,
                                                    const float* __restrict__ W1,
                                                    const float* __restrict__ b1,
                                                    const float* __restrict__ W2,
                                                    const float* __restrict__ b2,
                                                    float* __restrict__ sexp, int N) {
    __shared__ float sT[64][H];
    __shared__ float tT[64][H];
    const int tid = threadIdx.x;
    const int block0 = blockIdx.x * 64;

    for (int i = tid; i < 64 * (H / 4); i += 256) {
        int r  = i / (H / 4);
        int c4 = i % (H / 4);
        int row = block0 + r;
        float4 val = (row < N) ? reinterpret_cast<const float4*>(s + (size_t)row * H)[c4]
                               : make_float4(0.f, 0.f, 0.f, 0.f);
        reinterpret_cast<float4*>(&sT[r][0])[c4] = val;
    }
    __syncthreads();

    const int c    = tid & 127;
    const int half = tid >> 7;
    float acc[32];

    // phase 1: t = tanh(s@W1 + b1)
#pragma unroll
    for (int j = 0; j < 32; ++j) acc[j] = 0.f;
    for (int i = 0; i < H; ++i) {
        float w = W1[i * H + c];
#pragma unroll
        for (int j = 0; j < 32; ++j) acc[j] += sT[half * 32 + j][i] * w;
    }
    float bb = b1[c];
#pragma unroll
    for (int j = 0; j < 32; ++j) tT[half * 32 + j][c] = tanhf(acc[j] + bb);
    __syncthreads();

    // phase 2: sexp = t@W2 + b2 over 3 column segments of 128
    for (int seg = 0; seg < 3; ++seg) {
        int col = seg * 128 + c;
#pragma unroll
        for (int j = 0; j < 32; ++j) acc[j] = 0.f;
        for (int i = 0; i < H; ++i) {
            float w = W2[i * 384 + col];
#pragma unroll
            for (int j = 0; j < 32; ++j) acc[j] += tT[half * 32 + j][i] * w;
        }
        float bb2 = b2[col];
#pragma unroll
        for (int j = 0; j < 32; ++j) {
            int row = block0 + half * 32 + j;
            if (row < N) sexp[(size_t)row * 384 + col] = acc[j] + bb2;
        }
    }
}

// ---------------- edge scatter: 256 threads = 2 edges per block ----------------
__global__ __launch_bounds__(256) void edge_kernel(const int* __restrict__ ei,
                                                   const float* __restrict__ d_ij,
                                                   const float* __restrict__ dir_ij,
                                                   const float* __restrict__ sexp,
                                                   const float* __restrict__ v,
                                                   const float* __restrict__ invd,
                                                   const float* __restrict__ Wd,
                                                   const float* __restrict__ bd,
                                                   float* __restrict__ out_v,
                                                   float* __restrict__ out_s, int E) {
    const int e = blockIdx.x * 2 + (threadIdx.x >> 7);
    if (e >= E) return;
    const int k = threadIdx.x & 127;
    const int src = ei[e];
    const int dst = ei[E + e];
    const float d = d_ij[e];
    const float w = invd[dst];
    const float dir0 = dir_ij[e * 3 + 0];
    const float dir1 = dir_ij[e * 3 + 1];
    const float dir2 = dir_ij[e * 3 + 2];

    const float* se = sexp + (size_t)src * 384;
    float dv_v = se[k]       * (d * Wd[k]       + bd[k]);
    float dsv  = se[128 + k] * (d * Wd[128 + k] + bd[128 + k]);
    float dvr  = se[256 + k] * (d * Wd[256 + k] + bd[256 + k]);

    const float* vs = v + (size_t)src * 384;
    float dv0 = dvr * dir0 + dv_v * vs[k];
    float dv1 = dvr * dir1 + dv_v * vs[128 + k];
    float dv2 = dvr * dir2 + dv_v * vs[256 + k];

    atomicAdd(&out_s[(size_t)dst * H + k], dsv * w);
    float* ov = out_v + (size_t)dst * 384;
    atomicAdd(&ov[k],       dv0 * w);
    atomicAdd(&ov[128 + k], dv1 * w);
    atomicAdd(&ov[256 + k], dv2 * w);
}

extern "C" void kernel_launch(void* const* d_in, const int* in_sizes, int n_in,
                              void* d_out, int out_size, void* d_ws, size_t ws_size,
                              hipStream_t stream) {
    const float* v      = (const float*)d_in[0];
    const float* s      = (const float*)d_in[1];
    const int*   ei     = (const int*)  d_in[2];
    const float* d_ij   = (const float*)d_in[3];
    const float* dir_ij = (const float*)d_in[4];
    const float* W1     = (const float*)d_in[5];
    const float* b1     = (const float*)d_in[6];
    const float* W2     = (const float*)d_in[7];
    const float* b2     = (const float*)d_in[8];
    const float* Wd     = (const float*)d_in[9];
    const float* bd     = (const float*)d_in[10];

    const int N = in_sizes[1] / H;        // s is [N, H]
    const int E = in_sizes[2] / 2;        // edge_index is [2, E]

    // workspace layout
    char* ws = (char*)d_ws;
    float* sexp = (float*)ws;                                   // N*384 floats
    size_t off_cnt = (size_t)N * 384 * sizeof(float);
    off_cnt = (off_cnt + 255) & ~(size_t)255;
    int*   cnt  = (int*)(ws + off_cnt);                         // N ints
    float* invd = (float*)(ws + off_cnt + (((size_t)N * 4 + 255) & ~(size_t)255));

    float* out_v = (float*)d_out;                               // N*3*H
    float* out_s = out_v + (size_t)N * 3 * H;                   // N*H

    hipMemsetAsync(cnt, 0, (size_t)N * sizeof(int), stream);

    count_kernel<<<(E + 255) / 256, 256, 0, stream>>>(ei, cnt, E);
    denom_kernel<<<(N + 255) / 256, 256, 0, stream>>>(cnt, invd, N);
    embed_kernel<<<(N + 63) / 64, 256, 0, stream>>>(s, W1, b1, W2, b2, sexp, N);

    int nv4 = N * 3 * H / 4;
    int ns4 = N * H / 4;
    init_kernel<<<2048, 256, 0, stream>>>((const float4*)v, (const float4*)s,
                                          (float4*)d_out, nv4, ns4);

    edge_kernel<<<(E + 1) / 2, 256, 0, stream>>>(ei, d_ij, dir_ij, sexp, v, invd, Wd, bd,
                                                 out_v, out_s, E);
}

// Round 3
// 887.368 us; speedup vs baseline: 1.4714x; 1.4714x over previous
//
#include <hip/hip_runtime.h>

#define H 128

// ---------------- count per destination node ----------------
__global__ __launch_bounds__(256) void count_kernel(const int* __restrict__ ei,
                                                    int* __restrict__ cnt, int E) {
    int i = blockIdx.x * 256 + threadIdx.x;
    if (i < E) atomicAdd(&cnt[ei[E + i]], 1);
}

// ---------------- single-block exclusive scan: rowstart/cursor ----------------
__global__ __launch_bounds__(256) void scan_kernel(const int* __restrict__ cnt,
                                                   int* __restrict__ rowstart,
                                                   int* __restrict__ cursor, int N) {
    __shared__ int wsum[4];
    __shared__ int ctot_s;
    const int tid  = threadIdx.x;
    const int lane = tid & 63;
    const int wid  = tid >> 6;
    int base = 0;
    for (int start = 0; start < N; start += 256) {
        int i   = start + tid;
        int val = (i < N) ? cnt[i] : 0;
        int x   = val;
#pragma unroll
        for (int off = 1; off < 64; off <<= 1) {
            int y = __shfl_up(x, off, 64);
            if (lane >= off) x += y;
        }
        if (lane == 63) wsum[wid] = x;
        __syncthreads();
        if (tid == 0) {
            int a = 0;
#pragma unroll
            for (int w2 = 0; w2 < 4; ++w2) { int t = wsum[w2]; wsum[w2] = a; a += t; }
            ctot_s = a;
        }
        __syncthreads();
        int excl = base + wsum[wid] + x - val;
        if (i < N) { rowstart[i] = excl; cursor[i] = excl; }
        base += ctot_s;
        __syncthreads();
    }
    if (tid == 0) rowstart[N] = base;
}

// ---------------- bucket edge ids by destination ----------------
__global__ __launch_bounds__(256) void scatter_kernel(const int* __restrict__ ei,
                                                      int* __restrict__ cursor,
                                                      int* __restrict__ eids, int E) {
    int e = blockIdx.x * 256 + threadIdx.x;
    if (e < E) {
        int dst = ei[E + e];
        int pos = atomicAdd(&cursor[dst], 1);
        eids[pos] = e;
    }
}

// ---------------- fused embed net: sexp = tanh(s@W1+b1)@W2+b2 ----------------
// 64 rows/block, 256 threads: col = tid&127, half = tid>>7 handles 32 rows.
// LDS reads are wave-broadcast float4 (same address across lanes) -> conflict-free.
__global__ __launch_bounds__(256) void embed_kernel(const float* __restrict__ s,
                                                    const float* __restrict__ W1,
                                                    const float* __restrict__ b1,
                                                    const float* __restrict__ W2,
                                                    const float* __restrict__ b2,
                                                    float* __restrict__ sexp, int N) {
    __shared__ float sT[64][H];
    __shared__ float tT[64][H];
    const int tid    = threadIdx.x;
    const int block0 = blockIdx.x * 64;

    for (int i = tid; i < 64 * (H / 4); i += 256) {
        int r   = i / (H / 4);
        int c4  = i % (H / 4);
        int row = block0 + r;
        float4 val = (row < N) ? reinterpret_cast<const float4*>(s + (size_t)row * H)[c4]
                               : make_float4(0.f, 0.f, 0.f, 0.f);
        reinterpret_cast<float4*>(&sT[r][0])[c4] = val;
    }
    __syncthreads();

    const int c    = tid & 127;
    const int half = tid >> 7;
    float acc[32];

    // phase 1: t = tanh(s@W1 + b1)
#pragma unroll
    for (int j = 0; j < 32; ++j) acc[j] = 0.f;
    for (int i = 0; i < H; i += 4) {
        float w0 = W1[i * H + c];
        float w1 = W1[(i + 1) * H + c];
        float w2 = W1[(i + 2) * H + c];
        float w3 = W1[(i + 3) * H + c];
#pragma unroll
        for (int j = 0; j < 32; ++j) {
            float4 sv = *reinterpret_cast<const float4*>(&sT[half * 32 + j][i]);
            acc[j] = fmaf(sv.x, w0, fmaf(sv.y, w1, fmaf(sv.z, w2, fmaf(sv.w, w3, acc[j]))));
        }
    }
    float bb = b1[c];
#pragma unroll
    for (int j = 0; j < 32; ++j) tT[half * 32 + j][c] = tanhf(acc[j] + bb);
    __syncthreads();

    // phase 2: sexp = t@W2 + b2 over 3 column segments of 128
    for (int seg = 0; seg < 3; ++seg) {
        int col = seg * 128 + c;
#pragma unroll
        for (int j = 0; j < 32; ++j) acc[j] = 0.f;
        for (int i = 0; i < H; i += 4) {
            float w0 = W2[i * 384 + col];
            float w1 = W2[(i + 1) * 384 + col];
            float w2 = W2[(i + 2) * 384 + col];
            float w3 = W2[(i + 3) * 384 + col];
#pragma unroll
            for (int j = 0; j < 32; ++j) {
                float4 tv = *reinterpret_cast<const float4*>(&tT[half * 32 + j][i]);
                acc[j] = fmaf(tv.x, w0, fmaf(tv.y, w1, fmaf(tv.z, w2, fmaf(tv.w, w3, acc[j]))));
            }
        }
        float bb2 = b2[col];
#pragma unroll
        for (int j = 0; j < 32; ++j) {
            int row = block0 + half * 32 + j;
            if (row < N) sexp[(size_t)row * 384 + col] = acc[j] + bb2;
        }
    }
}

// ---------------- CSR gather: 2 nodes per 256-thread block ----------------
// Writes FINAL outputs (v + dv_agg, s + ds_agg) -- no atomics, no init pass.
__global__ __launch_bounds__(256) void gather_kernel(const int* __restrict__ ei,
                                                     const float* __restrict__ d_ij,
                                                     const float* __restrict__ dir_ij,
                                                     const float* __restrict__ sexp,
                                                     const float* __restrict__ v,
                                                     const float* __restrict__ s,
                                                     const int* __restrict__ rowstart,
                                                     const int* __restrict__ rowend,
                                                     const int* __restrict__ eids,
                                                     const float* __restrict__ Wd,
                                                     const float* __restrict__ bd,
                                                     float* __restrict__ out_v,
                                                     float* __restrict__ out_s, int N) {
    const int n = blockIdx.x * 2 + (threadIdx.x >> 7);
    if (n >= N) return;
    const int k   = threadIdx.x & 127;
    const int beg = rowstart[n];
    const int end = rowend[n];

    const float wd0 = Wd[k],       bd0 = bd[k];
    const float wd1 = Wd[128 + k], bd1 = bd[128 + k];
    const float wd2 = Wd[256 + k], bd2 = bd[256 + k];

    float a0 = 0.f, a1 = 0.f, a2 = 0.f, as = 0.f;
    for (int j = beg; j < end; ++j) {
        int e   = eids[j];
        int src = ei[e];
        float d  = d_ij[e];
        float q0 = dir_ij[e * 3 + 0];
        float q1 = dir_ij[e * 3 + 1];
        float q2 = dir_ij[e * 3 + 2];
        const float* se = sexp + (size_t)src * 384;
        const float* vs = v + (size_t)src * 384;
        float dvv = se[k]       * fmaf(d, wd0, bd0);
        float dss = se[128 + k] * fmaf(d, wd1, bd1);
        float dvr = se[256 + k] * fmaf(d, wd2, bd2);
        a0 = fmaf(dvr, q0, fmaf(dvv, vs[k],       a0));
        a1 = fmaf(dvr, q1, fmaf(dvv, vs[128 + k], a1));
        a2 = fmaf(dvr, q2, fmaf(dvv, vs[256 + k], a2));
        as += dss;
    }
    int c = end - beg;
    float inv = 1.0f / (float)(c > 1 ? c : 1);
    size_t vo = (size_t)n * 384;
    out_v[vo + k]       = v[vo + k]       + a0 * inv;
    out_v[vo + 128 + k] = v[vo + 128 + k] + a1 * inv;
    out_v[vo + 256 + k] = v[vo + 256 + k] + a2 * inv;
    out_s[(size_t)n * H + k] = s[(size_t)n * H + k] + as * inv;
}

extern "C" void kernel_launch(void* const* d_in, const int* in_sizes, int n_in,
                              void* d_out, int out_size, void* d_ws, size_t ws_size,
                              hipStream_t stream) {
    const float* v      = (const float*)d_in[0];
    const float* s      = (const float*)d_in[1];
    const int*   ei     = (const int*)  d_in[2];
    const float* d_ij   = (const float*)d_in[3];
    const float* dir_ij = (const float*)d_in[4];
    const float* W1     = (const float*)d_in[5];
    const float* b1     = (const float*)d_in[6];
    const float* W2     = (const float*)d_in[7];
    const float* b2     = (const float*)d_in[8];
    const float* Wd     = (const float*)d_in[9];
    const float* bd     = (const float*)d_in[10];

    const int N = in_sizes[1] / H;        // s is [N, H]
    const int E = in_sizes[2] / 2;        // edge_index is [2, E]

    // workspace layout
    char* ws = (char*)d_ws;
    size_t off = 0;
    float* sexp = (float*)(ws + off);  off += (size_t)N * 384 * sizeof(float);
    off = (off + 255) & ~(size_t)255;
    int* cnt      = (int*)(ws + off);  off += (size_t)N * sizeof(int);
    off = (off + 255) & ~(size_t)255;
    int* rowstart = (int*)(ws + off);  off += (size_t)(N + 1) * sizeof(int);
    off = (off + 255) & ~(size_t)255;
    int* cursor   = (int*)(ws + off);  off += (size_t)N * sizeof(int);
    off = (off + 255) & ~(size_t)255;
    int* eids     = (int*)(ws + off);  off += (size_t)E * sizeof(int);

    float* out_v = (float*)d_out;                 // N*3*H
    float* out_s = out_v + (size_t)N * 3 * H;     // N*H

    hipMemsetAsync(cnt, 0, (size_t)N * sizeof(int), stream);

    count_kernel<<<(E + 255) / 256, 256, 0, stream>>>(ei, cnt, E);
    scan_kernel<<<1, 256, 0, stream>>>(cnt, rowstart, cursor, N);
    scatter_kernel<<<(E + 255) / 256, 256, 0, stream>>>(ei, cursor, eids, E);
    embed_kernel<<<(N + 63) / 64, 256, 0, stream>>>(s, W1, b1, W2, b2, sexp, N);
    gather_kernel<<<(N + 1) / 2, 256, 0, stream>>>(ei, d_ij, dir_ij, sexp, v, s,
                                                   rowstart, cursor, eids, Wd, bd,
                                                   out_v, out_s, N);
}

// Round 4
// 502.940 us; speedup vs baseline: 2.5960x; 1.7644x over previous
//
#include <hip/hip_runtime.h>

#define H 128

typedef __attribute__((ext_vector_type(8))) short short8;   // bf16x8 fragment (4 VGPRs)
typedef __attribute__((ext_vector_type(4))) float floatx4;  // f32x4 accumulator

__device__ inline ushort f2bf(float f) {
    unsigned u = __float_as_uint(f);
    unsigned r = u + 0x7fff + ((u >> 16) & 1);   // RNE
    return (ushort)(r >> 16);
}
__device__ inline float bf2f(ushort u) {
    return __uint_as_float(((unsigned)u) << 16);
}

// ---------------- count per destination node ----------------
__global__ __launch_bounds__(256) void count_kernel(const int* __restrict__ ei,
                                                    int* __restrict__ cnt, int E) {
    int i = blockIdx.x * 256 + threadIdx.x;
    if (i < E) atomicAdd(&cnt[ei[E + i]], 1);
}

// ---------------- hierarchical exclusive scan (N=50000 -> 196 blocks) ----------------
__global__ __launch_bounds__(256) void scanA_kernel(const int* __restrict__ cnt,
                                                    int* __restrict__ lexcl,
                                                    int* __restrict__ bsum, int N) {
    __shared__ int wsum[4];
    int i = blockIdx.x * 256 + threadIdx.x;
    int lane = threadIdx.x & 63, wid = threadIdx.x >> 6;
    int val = (i < N) ? cnt[i] : 0;
    int x = val;
#pragma unroll
    for (int off = 1; off < 64; off <<= 1) {
        int y = __shfl_up(x, off, 64);
        if (lane >= off) x += y;
    }
    if (lane == 63) wsum[wid] = x;
    __syncthreads();
    if (threadIdx.x == 0) {
        int a = 0;
#pragma unroll
        for (int w = 0; w < 4; ++w) { int t = wsum[w]; wsum[w] = a; a += t; }
        bsum[blockIdx.x] = a;
    }
    __syncthreads();
    if (i < N) lexcl[i] = wsum[wid] + x - val;
}

// single block scans the <=256 block sums in-place (exclusive)
__global__ __launch_bounds__(256) void scanB_kernel(int* __restrict__ bsum, int nb) {
    __shared__ int wsum[4];
    int lane = threadIdx.x & 63, wid = threadIdx.x >> 6;
    int val = (threadIdx.x < nb) ? bsum[threadIdx.x] : 0;
    int x = val;
#pragma unroll
    for (int off = 1; off < 64; off <<= 1) {
        int y = __shfl_up(x, off, 64);
        if (lane >= off) x += y;
    }
    if (lane == 63) wsum[wid] = x;
    __syncthreads();
    if (threadIdx.x == 0) {
        int a = 0;
#pragma unroll
        for (int w = 0; w < 4; ++w) { int t = wsum[w]; wsum[w] = a; a += t; }
    }
    __syncthreads();
    if (threadIdx.x < nb) bsum[threadIdx.x] = wsum[wid] + x - val;
}

__global__ __launch_bounds__(256) void scanC_kernel(const int* __restrict__ boff,
                                                    int* __restrict__ rowstart,
                                                    int* __restrict__ cursor, int N) {
    int i = blockIdx.x * 256 + threadIdx.x;
    if (i < N) {
        int v = rowstart[i] + boff[blockIdx.x];
        rowstart[i] = v;
        cursor[i] = v;
    }
}

// ---------------- bucket edge ids by destination ----------------
__global__ __launch_bounds__(256) void scatter_kernel(const int* __restrict__ ei,
                                                      int* __restrict__ cursor,
                                                      int* __restrict__ eids, int E) {
    int e = blockIdx.x * 256 + threadIdx.x;
    if (e < E) {
        int dst = ei[E + e];
        int pos = atomicAdd(&cursor[dst], 1);
        eids[pos] = e;
    }
}

// ---------------- prep: W1^T / W2^T as bf16 images, pre-swizzled for LDS ----------------
// image layout (per 128-col segment): img[n*128 + (k ^ ((n&7)<<3))] = bf16(W[k][n])
__global__ __launch_bounds__(256) void prep_w(const float* __restrict__ W1,
                                              const float* __restrict__ W2,
                                              ushort* __restrict__ w1img,
                                              ushort* __restrict__ w2img) {
    int t = blockIdx.x * 256 + threadIdx.x;
    if (t < 16384) {
        int n = t >> 7, ks = t & 127;
        int k = ks ^ ((n & 7) << 3);
        w1img[t] = f2bf(W1[k * 128 + n]);
    } else if (t < 65536) {
        int u = t - 16384;
        int n = u >> 7, ks = u & 127;       // n in 0..383
        int k = ks ^ ((n & 7) << 3);
        w2img[u] = f2bf(W2[k * 384 + n]);
    }
}

// ---------------- MFMA embed: sexp = tanh(s@W1+b1)@W2+b2, bf16 out ----------------
// 64 rows/block, 4 waves x 16-row strips. LDS: sA 16K | wB 32K | tT 16K = 64K.
__device__ inline short8 frag_ld(const ushort* base, int row, int kb, int l) {
    int byteoff = row * 256 + ((kb * 64 + ((l >> 4) << 4)) ^ ((row & 7) << 4));
    return *reinterpret_cast<const short8*>(reinterpret_cast<const char*>(base) + byteoff);
}

__global__ __launch_bounds__(256) void embed_mfma(const float* __restrict__ s,
                                                  const ushort* __restrict__ w1img,
                                                  const ushort* __restrict__ w2img,
                                                  const float* __restrict__ b1,
                                                  const float* __restrict__ b2,
                                                  ushort* __restrict__ sexp, int N) {
    __shared__ ushort sA[64 * 128];
    __shared__ ushort wB[128 * 128];
    __shared__ ushort tT[64 * 128];
    const int tid = threadIdx.x;
    const int block0 = blockIdx.x * 64;
    const int wv = tid >> 6;
    const int l  = tid & 63;
    const int row0 = wv * 16;

    // stage sA: bf16, swizzled
    for (int ch = tid; ch < 2048; ch += 256) {
        int r = ch >> 5, c4 = ch & 31;
        int grow = block0 + r;
        float4 val = (grow < N) ? reinterpret_cast<const float4*>(s)[(size_t)grow * 32 + c4]
                                : make_float4(0.f, 0.f, 0.f, 0.f);
        ushort4 h;
        h.x = f2bf(val.x); h.y = f2bf(val.y); h.z = f2bf(val.z); h.w = f2bf(val.w);
        int byteoff = r * 256 + ((c4 * 8) ^ ((r & 7) << 4));
        *reinterpret_cast<ushort4*>(reinterpret_cast<char*>(sA) + byteoff) = h;
    }
    // stage W1 image: straight 32 KB copy
    for (int ch = tid; ch < 2048; ch += 256)
        reinterpret_cast<float4*>(wB)[ch] = reinterpret_cast<const float4*>(w1img)[ch];
    __syncthreads();

    // phase 1: T = tanh(s@W1 + b1)
    floatx4 acc[8];
#pragma unroll
    for (int nt = 0; nt < 8; ++nt) acc[nt] = (floatx4)(0.f);
#pragma unroll
    for (int kb = 0; kb < 4; ++kb) {
        short8 a = frag_ld(sA, row0 + (l & 15), kb, l);
#pragma unroll
        for (int nt = 0; nt < 8; ++nt) {
            short8 b = frag_ld(wB, nt * 16 + (l & 15), kb, l);
            acc[nt] = __builtin_amdgcn_mfma_f32_16x16x32_bf16(a, b, acc[nt], 0, 0, 0);
        }
    }
    {
        int crow0 = row0 + ((l >> 4) << 2);
        int ccol  = l & 15;
#pragma unroll
        for (int nt = 0; nt < 8; ++nt) {
            int col = nt * 16 + ccol;
            float bb = b1[col];
#pragma unroll
            for (int r = 0; r < 4; ++r) {
                int rr = crow0 + r;
                float t = tanhf(acc[nt][r] + bb);
                int byteoff = rr * 256 + ((col * 2) ^ ((rr & 7) << 4));
                *reinterpret_cast<ushort*>(reinterpret_cast<char*>(tT) + byteoff) = f2bf(t);
            }
        }
    }
    __syncthreads();

    // phase 2: sexp = T@W2 + b2, three 128-col segments
    for (int seg = 0; seg < 3; ++seg) {
        for (int ch = tid; ch < 2048; ch += 256)
            reinterpret_cast<float4*>(wB)[ch] =
                reinterpret_cast<const float4*>(w2img + seg * 16384)[ch];
        __syncthreads();
        floatx4 acc2[8];
#pragma unroll
        for (int nt = 0; nt < 8; ++nt) acc2[nt] = (floatx4)(0.f);
#pragma unroll
        for (int kb = 0; kb < 4; ++kb) {
            short8 a = frag_ld(tT, row0 + (l & 15), kb, l);
#pragma unroll
            for (int nt = 0; nt < 8; ++nt) {
                short8 b = frag_ld(wB, nt * 16 + (l & 15), kb, l);
                acc2[nt] = __builtin_amdgcn_mfma_f32_16x16x32_bf16(a, b, acc2[nt], 0, 0, 0);
            }
        }
        int crow0 = row0 + ((l >> 4) << 2);
#pragma unroll
        for (int nt = 0; nt < 8; ++nt) {
            int col = seg * 128 + nt * 16 + (l & 15);
            float bb = b2[col];
#pragma unroll
            for (int r = 0; r < 4; ++r) {
                int grow = block0 + crow0 + r;
                if (grow < N) sexp[(size_t)grow * 384 + col] = f2bf(acc2[nt][r] + bb);
            }
        }
        __syncthreads();
    }
}

// ---------------- CSR gather: 2 nodes per 256-thread block ----------------
__global__ __launch_bounds__(256) void gather_kernel(const int* __restrict__ ei,
                                                     const float* __restrict__ d_ij,
                                                     const float* __restrict__ dir_ij,
                                                     const ushort* __restrict__ sexp,
                                                     const float* __restrict__ v,
                                                     const float* __restrict__ s,
                                                     const int* __restrict__ rowstart,
                                                     const int* __restrict__ rowend,
                                                     const int* __restrict__ eids,
                                                     const float* __restrict__ Wd,
                                                     const float* __restrict__ bd,
                                                     float* __restrict__ out_v,
                                                     float* __restrict__ out_s, int N) {
    const int n = blockIdx.x * 2 + (threadIdx.x >> 7);
    if (n >= N) return;
    const int k   = threadIdx.x & 127;
    const int beg = rowstart[n];
    const int end = rowend[n];

    const float wd0 = Wd[k],       bd0 = bd[k];
    const float wd1 = Wd[128 + k], bd1 = bd[128 + k];
    const float wd2 = Wd[256 + k], bd2 = bd[256 + k];

    float a0 = 0.f, a1 = 0.f, a2 = 0.f, as = 0.f;
    for (int j = beg; j < end; ++j) {
        int e   = eids[j];
        int src = ei[e];
        float d  = d_ij[e];
        float q0 = dir_ij[e * 3 + 0];
        float q1 = dir_ij[e * 3 + 1];
        float q2 = dir_ij[e * 3 + 2];
        const ushort* se = sexp + (size_t)src * 384;
        const float*  vs = v + (size_t)src * 384;
        float dvv = bf2f(se[k])       * fmaf(d, wd0, bd0);
        float dss = bf2f(se[128 + k]) * fmaf(d, wd1, bd1);
        float dvr = bf2f(se[256 + k]) * fmaf(d, wd2, bd2);
        a0 = fmaf(dvr, q0, fmaf(dvv, vs[k],       a0));
        a1 = fmaf(dvr, q1, fmaf(dvv, vs[128 + k], a1));
        a2 = fmaf(dvr, q2, fmaf(dvv, vs[256 + k], a2));
        as += dss;
    }
    int c = end - beg;
    float inv = 1.0f / (float)(c > 1 ? c : 1);
    size_t vo = (size_t)n * 384;
    out_v[vo + k]       = v[vo + k]       + a0 * inv;
    out_v[vo + 128 + k] = v[vo + 128 + k] + a1 * inv;
    out_v[vo + 256 + k] = v[vo + 256 + k] + a2 * inv;
    out_s[(size_t)n * H + k] = s[(size_t)n * H + k] + as * inv;
}

extern "C" void kernel_launch(void* const* d_in, const int* in_sizes, int n_in,
                              void* d_out, int out_size, void* d_ws, size_t ws_size,
                              hipStream_t stream) {
    const float* v      = (const float*)d_in[0];
    const float* s      = (const float*)d_in[1];
    const int*   ei     = (const int*)  d_in[2];
    const float* d_ij   = (const float*)d_in[3];
    const float* dir_ij = (const float*)d_in[4];
    const float* W1     = (const float*)d_in[5];
    const float* b1     = (const float*)d_in[6];
    const float* W2     = (const float*)d_in[7];
    const float* b2     = (const float*)d_in[8];
    const float* Wd     = (const float*)d_in[9];
    const float* bd     = (const float*)d_in[10];

    const int N  = in_sizes[1] / H;       // s is [N, H]
    const int E  = in_sizes[2] / 2;       // edge_index is [2, E]
    const int nb = (N + 255) / 256;       // scan blocks (196 <= 256)

    // workspace layout
    char* ws = (char*)d_ws;
    size_t off = 0;
    ushort* sexp  = (ushort*)(ws + off); off += (size_t)N * 384 * sizeof(ushort);
    off = (off + 255) & ~(size_t)255;
    ushort* w1img = (ushort*)(ws + off); off += 16384 * sizeof(ushort);
    off = (off + 255) & ~(size_t)255;
    ushort* w2img = (ushort*)(ws + off); off += 49152 * sizeof(ushort);
    off = (off + 255) & ~(size_t)255;
    int* cnt      = (int*)(ws + off);    off += (size_t)N * sizeof(int);
    off = (off + 255) & ~(size_t)255;
    int* rowstart = (int*)(ws + off);    off += (size_t)(N + 1) * sizeof(int);
    off = (off + 255) & ~(size_t)255;
    int* cursor   = (int*)(ws + off);    off += (size_t)N * sizeof(int);
    off = (off + 255) & ~(size_t)255;
    int* bsum     = (int*)(ws + off);    off += (size_t)nb * sizeof(int);
    off = (off + 255) & ~(size_t)255;
    int* eids     = (int*)(ws + off);    off += (size_t)E * sizeof(int);

    float* out_v = (float*)d_out;                 // N*3*H
    float* out_s = out_v + (size_t)N * 3 * H;     // N*H

    hipMemsetAsync(cnt, 0, (size_t)N * sizeof(int), stream);

    count_kernel<<<(E + 255) / 256, 256, 0, stream>>>(ei, cnt, E);
    scanA_kernel<<<nb, 256, 0, stream>>>(cnt, rowstart, bsum, N);
    scanB_kernel<<<1, 256, 0, stream>>>(bsum, nb);
    scanC_kernel<<<nb, 256, 0, stream>>>(bsum, rowstart, cursor, N);
    scatter_kernel<<<(E + 255) / 256, 256, 0, stream>>>(ei, cursor, eids, E);

    prep_w<<<256, 256, 0, stream>>>(W1, W2, w1img, w2img);
    embed_mfma<<<(N + 63) / 64, 256, 0, stream>>>(s, w1img, w2img, b1, b2, sexp, N);

    gather_kernel<<<(N + 1) / 2, 256, 0, stream>>>(ei, d_ij, dir_ij, sexp, v, s,
                                                   rowstart, cursor, eids, Wd, bd,
                                                   out_v, out_s, N);
}

// Round 6
// 467.004 us; speedup vs baseline: 2.7958x; 1.0770x over previous
//
#include <hip/hip_runtime.h>

#define H 128
#define MAXE 32

typedef __attribute__((ext_vector_type(8))) short short8;   // bf16x8 fragment (4 VGPRs)
typedef __attribute__((ext_vector_type(4))) float floatx4;  // f32x4 accumulator

__device__ inline ushort f2bf(float f) {
    unsigned u = __float_as_uint(f);
    unsigned r = u + 0x7fff + ((u >> 16) & 1);   // RNE
    return (ushort)(r >> 16);
}
__device__ inline float bf2f(ushort u) {
    return __uint_as_float(((unsigned)u) << 16);
}

// ---------------- count per destination node ----------------
__global__ __launch_bounds__(256) void count_kernel(const int* __restrict__ ei,
                                                    int* __restrict__ cnt, int E) {
    int i = blockIdx.x * 256 + threadIdx.x;
    if (i < E) atomicAdd(&cnt[ei[E + i]], 1);
}

// ---------------- hierarchical exclusive scan ----------------
__global__ __launch_bounds__(256) void scanA_kernel(const int* __restrict__ cnt,
                                                    int* __restrict__ lexcl,
                                                    int* __restrict__ bsum, int N) {
    __shared__ int wsum[4];
    int i = blockIdx.x * 256 + threadIdx.x;
    int lane = threadIdx.x & 63, wid = threadIdx.x >> 6;
    int val = (i < N) ? cnt[i] : 0;
    int x = val;
#pragma unroll
    for (int off = 1; off < 64; off <<= 1) {
        int y = __shfl_up(x, off, 64);
        if (lane >= off) x += y;
    }
    if (lane == 63) wsum[wid] = x;
    __syncthreads();
    if (threadIdx.x == 0) {
        int a = 0;
#pragma unroll
        for (int w = 0; w < 4; ++w) { int t = wsum[w]; wsum[w] = a; a += t; }
        bsum[blockIdx.x] = a;
    }
    __syncthreads();
    if (i < N) lexcl[i] = wsum[wid] + x - val;
}

__global__ __launch_bounds__(256) void scanB_kernel(int* __restrict__ bsum, int nb) {
    __shared__ int wsum[4];
    int lane = threadIdx.x & 63, wid = threadIdx.x >> 6;
    int val = (threadIdx.x < nb) ? bsum[threadIdx.x] : 0;
    int x = val;
#pragma unroll
    for (int off = 1; off < 64; off <<= 1) {
        int y = __shfl_up(x, off, 64);
        if (lane >= off) x += y;
    }
    if (lane == 63) wsum[wid] = x;
    __syncthreads();
    if (threadIdx.x == 0) {
        int a = 0;
#pragma unroll
        for (int w = 0; w < 4; ++w) { int t = wsum[w]; wsum[w] = a; a += t; }
    }
    __syncthreads();
    if (threadIdx.x < nb) bsum[threadIdx.x] = wsum[wid] + x - val;
}

__global__ __launch_bounds__(256) void scanC_kernel(const int* __restrict__ boff,
                                                    int* __restrict__ rowstart,
                                                    int* __restrict__ cursor, int N) {
    int i = blockIdx.x * 256 + threadIdx.x;
    if (i < N) {
        int v = rowstart[i] + boff[blockIdx.x];
        rowstart[i] = v;
        cursor[i] = v;
    }
}

// ---------------- bucket edge ids by destination ----------------
__global__ __launch_bounds__(256) void scatter_kernel(const int* __restrict__ ei,
                                                      int* __restrict__ cursor,
                                                      int* __restrict__ eids, int E) {
    int e = blockIdx.x * 256 + threadIdx.x;
    if (e < E) {
        int dst = ei[E + e];
        int pos = atomicAdd(&cursor[dst], 1);
        eids[pos] = e;
    }
}

// ---------------- prep: W images (swizzled bf16) + v -> gtab bf16 half ----------------
// w image layout (per 128-col segment): img[n*128 + (k ^ ((n&7)<<3))] = bf16(W[k][n])
// gtab row: [0..383]=sexp (written by embed), [384..767]=bf16(v[row])
__global__ __launch_bounds__(256) void prep_kernel(const float* __restrict__ W1,
                                                   const float* __restrict__ W2,
                                                   const float* __restrict__ v,
                                                   ushort* __restrict__ w1img,
                                                   ushort* __restrict__ w2img,
                                                   ushort* __restrict__ gtab, int N) {
    int t = blockIdx.x * 256 + threadIdx.x;
    if (t < 16384) {
        int n = t >> 7, ks = t & 127;
        int k = ks ^ ((n & 7) << 3);
        w1img[t] = f2bf(W1[k * 128 + n]);
    } else if (t < 65536) {
        int u = t - 16384;
        int n = u >> 7, ks = u & 127;       // n in 0..383
        int k = ks ^ ((n & 7) << 3);
        w2img[u] = f2bf(W2[k * 384 + n]);
    }
    int total4 = N * 96;                     // N*384/4
    for (int i = t; i < total4; i += gridDim.x * 256) {
        float4 val = reinterpret_cast<const float4*>(v)[i];
        int row = i / 96, c4 = i % 96;
        ushort4 h;
        h.x = f2bf(val.x); h.y = f2bf(val.y); h.z = f2bf(val.z); h.w = f2bf(val.w);
        *reinterpret_cast<ushort4*>(gtab + (size_t)row * 768 + 384 + c4 * 4) = h;
    }
}

// ---------------- MFMA embed: gtab[:,0:384] = tanh(s@W1+b1)@W2+b2, bf16 ----------------
// 64 rows/block, 4 waves x 16-row strips. LDS: sA 16K | wB 32K | tT 16K = 64K.
__device__ inline short8 frag_ld(const ushort* base, int row, int kb, int l) {
    int byteoff = row * 256 + ((kb * 64 + ((l >> 4) << 4)) ^ ((row & 7) << 4));
    return *reinterpret_cast<const short8*>(reinterpret_cast<const char*>(base) + byteoff);
}

__global__ __launch_bounds__(256) void embed_mfma(const float* __restrict__ s,
                                                  const ushort* __restrict__ w1img,
                                                  const ushort* __restrict__ w2img,
                                                  const float* __restrict__ b1,
                                                  const float* __restrict__ b2,
                                                  ushort* __restrict__ gtab, int N) {
    __shared__ ushort sA[64 * 128];
    __shared__ ushort wB[128 * 128];
    __shared__ ushort tT[64 * 128];
    const int tid = threadIdx.x;
    const int block0 = blockIdx.x * 64;
    const int wv = tid >> 6;
    const int l  = tid & 63;
    const int row0 = wv * 16;

    // stage sA: bf16, swizzled
    for (int ch = tid; ch < 2048; ch += 256) {
        int r = ch >> 5, c4 = ch & 31;
        int grow = block0 + r;
        float4 val = (grow < N) ? reinterpret_cast<const float4*>(s)[(size_t)grow * 32 + c4]
                                : make_float4(0.f, 0.f, 0.f, 0.f);
        ushort4 h;
        h.x = f2bf(val.x); h.y = f2bf(val.y); h.z = f2bf(val.z); h.w = f2bf(val.w);
        int byteoff = r * 256 + ((c4 * 8) ^ ((r & 7) << 4));
        *reinterpret_cast<ushort4*>(reinterpret_cast<char*>(sA) + byteoff) = h;
    }
    // stage W1 image: straight 32 KB copy
    for (int ch = tid; ch < 2048; ch += 256)
        reinterpret_cast<float4*>(wB)[ch] = reinterpret_cast<const float4*>(w1img)[ch];
    __syncthreads();

    // phase 1: T = tanh(s@W1 + b1)
    floatx4 acc[8];
#pragma unroll
    for (int nt = 0; nt < 8; ++nt) acc[nt] = (floatx4)(0.f);
#pragma unroll
    for (int kb = 0; kb < 4; ++kb) {
        short8 a = frag_ld(sA, row0 + (l & 15), kb, l);
#pragma unroll
        for (int nt = 0; nt < 8; ++nt) {
            short8 b = frag_ld(wB, nt * 16 + (l & 15), kb, l);
            acc[nt] = __builtin_amdgcn_mfma_f32_16x16x32_bf16(a, b, acc[nt], 0, 0, 0);
        }
    }
    {
        int crow0 = row0 + ((l >> 4) << 2);
        int ccol  = l & 15;
#pragma unroll
        for (int nt = 0; nt < 8; ++nt) {
            int col = nt * 16 + ccol;
            float bb = b1[col];
#pragma unroll
            for (int r = 0; r < 4; ++r) {
                int rr = crow0 + r;
                float t = tanhf(acc[nt][r] + bb);
                int byteoff = rr * 256 + ((col * 2) ^ ((rr & 7) << 4));
                *reinterpret_cast<ushort*>(reinterpret_cast<char*>(tT) + byteoff) = f2bf(t);
            }
        }
    }
    __syncthreads();

    // phase 2: sexp = T@W2 + b2, three 128-col segments
    for (int seg = 0; seg < 3; ++seg) {
        for (int ch = tid; ch < 2048; ch += 256)
            reinterpret_cast<float4*>(wB)[ch] =
                reinterpret_cast<const float4*>(w2img + seg * 16384)[ch];
        __syncthreads();
        floatx4 acc2[8];
#pragma unroll
        for (int nt = 0; nt < 8; ++nt) acc2[nt] = (floatx4)(0.f);
#pragma unroll
        for (int kb = 0; kb < 4; ++kb) {
            short8 a = frag_ld(tT, row0 + (l & 15), kb, l);
#pragma unroll
            for (int nt = 0; nt < 8; ++nt) {
                short8 b = frag_ld(wB, nt * 16 + (l & 15), kb, l);
                acc2[nt] = __builtin_amdgcn_mfma_f32_16x16x32_bf16(a, b, acc2[nt], 0, 0, 0);
            }
        }
        int crow0 = row0 + ((l >> 4) << 2);
#pragma unroll
        for (int nt = 0; nt < 8; ++nt) {
            int col = seg * 128 + nt * 16 + (l & 15);
            float bb = b2[col];
#pragma unroll
            for (int r = 0; r < 4; ++r) {
                int grow = block0 + crow0 + r;
                if (grow < N) gtab[(size_t)grow * 768 + col] = f2bf(acc2[nt][r] + bb);
            }
        }
        __syncthreads();
    }
}

// ---------------- CSR gather: 1 node per 128-thread block, LDS edge-meta ----------------
__global__ __launch_bounds__(128) void gather_kernel(const int* __restrict__ ei,
                                                     const float* __restrict__ d_ij,
                                                     const float* __restrict__ dir_ij,
                                                     const ushort* __restrict__ gtab,
                                                     const float* __restrict__ v,
                                                     const float* __restrict__ s,
                                                     const int* __restrict__ rowstart,
                                                     const int* __restrict__ rowend,
                                                     const int* __restrict__ eids,
                                                     const float* __restrict__ Wd,
                                                     const float* __restrict__ bd,
                                                     float* __restrict__ out_v,
                                                     float* __restrict__ out_s, int N) {
    __shared__ int   lsrc[MAXE];
    __shared__ float ld[MAXE], lq0[MAXE], lq1[MAXE], lq2[MAXE];
    const int n = blockIdx.x;
    const int k = threadIdx.x;
    const int beg = rowstart[n];
    const int deg = rowend[n] - beg;

    const float wd0 = Wd[k],       bd0 = bd[k];
    const float wd1 = Wd[128 + k], bd1 = bd[128 + k];
    const float wd2 = Wd[256 + k], bd2 = bd[256 + k];

    float a0 = 0.f, a1 = 0.f, a2 = 0.f, as = 0.f;
    for (int base = 0; base < deg; base += MAXE) {
        int cd = min(MAXE, deg - base);
        if (k < cd) {
            int e = eids[beg + base + k];
            lsrc[k] = ei[e];
            ld[k]   = d_ij[e];
            lq0[k]  = dir_ij[e * 3 + 0];
            lq1[k]  = dir_ij[e * 3 + 1];
            lq2[k]  = dir_ij[e * 3 + 2];
        }
        __syncthreads();
#pragma unroll 2
        for (int j = 0; j < cd; ++j) {
            const ushort* g = gtab + (size_t)lsrc[j] * 768;
            float se0 = bf2f(g[k]);
            float se1 = bf2f(g[128 + k]);
            float se2 = bf2f(g[256 + k]);
            float vv0 = bf2f(g[384 + k]);
            float vv1 = bf2f(g[512 + k]);
            float vv2 = bf2f(g[640 + k]);
            float d   = ld[j];
            float dvv = se0 * fmaf(d, wd0, bd0);
            float dss = se1 * fmaf(d, wd1, bd1);
            float dvr = se2 * fmaf(d, wd2, bd2);
            a0 = fmaf(dvr, lq0[j], fmaf(dvv, vv0, a0));
            a1 = fmaf(dvr, lq1[j], fmaf(dvv, vv1, a1));
            a2 = fmaf(dvr, lq2[j], fmaf(dvv, vv2, a2));
            as += dss;
        }
        __syncthreads();
    }
    float inv = 1.0f / (float)(deg > 1 ? deg : 1);
    size_t vo = (size_t)n * 384;
    out_v[vo + k]       = v[vo + k]       + a0 * inv;
    out_v[vo + 128 + k] = v[vo + 128 + k] + a1 * inv;
    out_v[vo + 256 + k] = v[vo + 256 + k] + a2 * inv;
    out_s[(size_t)n * H + k] = s[(size_t)n * H + k] + as * inv;
}

extern "C" void kernel_launch(void* const* d_in, const int* in_sizes, int n_in,
                              void* d_out, int out_size, void* d_ws, size_t ws_size,
                              hipStream_t stream) {
    const float* v      = (const float*)d_in[0];
    const float* s      = (const float*)d_in[1];
    const int*   ei     = (const int*)  d_in[2];
    const float* d_ij   = (const float*)d_in[3];
    const float* dir_ij = (const float*)d_in[4];
    const float* W1     = (const float*)d_in[5];
    const float* b1     = (const float*)d_in[6];
    const float* W2     = (const float*)d_in[7];
    const float* b2     = (const float*)d_in[8];
    const float* Wd     = (const float*)d_in[9];
    const float* bd     = (const float*)d_in[10];

    const int N  = in_sizes[1] / H;       // s is [N, H]
    const int E  = in_sizes[2] / 2;       // edge_index is [2, E]
    const int nb = (N + 255) / 256;       // scan blocks (<=256)

    // workspace layout
    char* ws = (char*)d_ws;
    size_t off = 0;
    ushort* gtab  = (ushort*)(ws + off); off += (size_t)N * 768 * sizeof(ushort);
    off = (off + 255) & ~(size_t)255;
    ushort* w1img = (ushort*)(ws + off); off += 16384 * sizeof(ushort);
    off = (off + 255) & ~(size_t)255;
    ushort* w2img = (ushort*)(ws + off); off += 49152 * sizeof(ushort);
    off = (off + 255) & ~(size_t)255;
    int* cnt      = (int*)(ws + off);    off += (size_t)N * sizeof(int);
    off = (off + 255) & ~(size_t)255;
    int* rowstart = (int*)(ws + off);    off += (size_t)(N + 1) * sizeof(int);
    off = (off + 255) & ~(size_t)255;
    int* cursor   = (int*)(ws + off);    off += (size_t)N * sizeof(int);
    off = (off + 255) & ~(size_t)255;
    int* bsum     = (int*)(ws + off);    off += (size_t)nb * sizeof(int);
    off = (off + 255) & ~(size_t)255;
    int* eids     = (int*)(ws + off);    off += (size_t)E * sizeof(int);

    float* out_v = (float*)d_out;                 // N*3*H
    float* out_s = out_v + (size_t)N * 3 * H;     // N*H

    hipMemsetAsync(cnt, 0, (size_t)N * sizeof(int), stream);

    count_kernel<<<(E + 255) / 256, 256, 0, stream>>>(ei, cnt, E);
    scanA_kernel<<<nb, 256, 0, stream>>>(cnt, rowstart, bsum, N);
    scanB_kernel<<<1, 256, 0, stream>>>(bsum, nb);
    scanC_kernel<<<nb, 256, 0, stream>>>(bsum, rowstart, cursor, N);
    scatter_kernel<<<(E + 255) / 256, 256, 0, stream>>>(ei, cursor, eids, E);

    prep_kernel<<<2048, 256, 0, stream>>>(W1, W2, v, w1img, w2img, gtab, N);
    embed_mfma<<<(N + 63) / 64, 256, 0, stream>>>(s, w1img, w2img, b1, b2, gtab, N);

    gather_kernel<<<N, 128, 0, stream>>>(ei, d_ij, dir_ij, gtab, v, s,
                                         rowstart, cursor, eids, Wd, bd,
                                         out_v, out_s, N);
}